// Round 8
// baseline (380.822 us; speedup 1.0000x reference)
//
#include <hip/hip_runtime.h>
#include <hip/hip_bf16.h>
#include <math.h>

#define BB 2
#define SS 2048
#define DD 2048
#define HH 16
#define DHH 128
#define MM (BB*SS)   // 4096

typedef __attribute__((ext_vector_type(8))) short bf16x8;
typedef __attribute__((ext_vector_type(4))) float f32x4;

#define AS1 __attribute__((address_space(1)))
#define AS3 __attribute__((address_space(3)))
#define GLOAD_LDS16(g, l) __builtin_amdgcn_global_load_lds((const AS1 void*)(g), (AS3 void*)(l), 16, 0, 0)

#if __has_builtin(__builtin_amdgcn_exp2f)
#define EXP2F(x) __builtin_amdgcn_exp2f(x)
#else
#define EXP2F(x) exp2f(x)
#endif

__device__ __forceinline__ float b2f(short s) {
  union { unsigned int u; float f; } v;
  v.u = ((unsigned int)(unsigned short)s) << 16;
  return v.f;
}
__device__ __forceinline__ short f2b(float f) {
  union { float f; unsigned int u; } v; v.f = f;
  unsigned int u = v.u;
  u += 0x7fffu + ((u >> 16) & 1u);   // round-to-nearest-even
  return (short)(u >> 16);
}
// fast round-half-up; valid for non-negative finite values
__device__ __forceinline__ short f2b_fast(float f) {
  union { float f; unsigned int u; } v; v.f = f;
  return (short)((v.u + 0x8000u) >> 16);
}

// ---- DPP helpers (VALU pipe, no LDS ops) ----
template<int CTRL>
__device__ __forceinline__ float dppf(float x) {
  int xi = __builtin_bit_cast(int, x);
  int r = __builtin_amdgcn_update_dpp(0, xi, CTRL, 0xf, 0xf, true);
  return __builtin_bit_cast(float, r);
}
__device__ __forceinline__ float rmax16(float x) {
  x = fmaxf(x, dppf<0xB1>(x));   // quad_perm xor1
  x = fmaxf(x, dppf<0x4E>(x));   // quad_perm xor2
  x = fmaxf(x, dppf<0x141>(x));  // row_half_mirror
  x = fmaxf(x, dppf<0x140>(x));  // row_mirror
  return x;
}
__device__ __forceinline__ float rsum16(float x) {
  x += dppf<0xB1>(x);
  x += dppf<0x4E>(x);
  x += dppf<0x141>(x);
  x += dppf<0x140>(x);
  return x;
}

// ---------------- fp32 -> bf16 convert, all 5 tensors in one launch ----------------
__global__ void cvt_all(const float* __restrict__ x,  const float* __restrict__ wq,
                        const float* __restrict__ wk, const float* __restrict__ wv,
                        const float* __restrict__ wo,
                        short* __restrict__ xb,  short* __restrict__ wqb,
                        short* __restrict__ wkb, short* __restrict__ wvb,
                        short* __restrict__ wob) {
  int i = blockIdx.x * blockDim.x + threadIdx.x;   // float4 index
  const float* src; short* dst; int off;
  if (i < 2097152) { src = x; dst = xb; off = i; }
  else {
    int j = i - 2097152;
    int w = j >> 20; off = j & 1048575;
    src = (w == 0) ? wq : (w == 1) ? wk : (w == 2) ? wv : wo;
    dst = (w == 0) ? wqb : (w == 1) ? wkb : (w == 2) ? wvb : wob;
  }
  float4 v = ((const float4*)src)[i < 2097152 ? off : off];
  short4 o;
  o.x = f2b(v.x); o.y = f2b(v.y); o.z = f2b(v.z); o.w = f2b(v.w);
  ((short4*)dst)[off] = o;
}

// =============== 256x128-tile 8-wave GEMM template (round-5 proven, 119.2 us) ====
// 8 waves as 4M x 2N (wave tile 64x64), BK=64. LDS: A tribuf 96K + B tribuf 48K
// = 144 KiB (1 block/CU). T2 swizzle via pre-swizzled global source
// (global_load_lds writes linearly). BOTH A and B staged 2 tiles ahead;
// counted vmcnt(6) (6 loads in flight, never drains mid-loop).
#define LDA3(b, mt, kk) (*(const bf16x8*)((const char*)smA + (b)*32768 + \
    (wm*64 + (mt)*16 + l16)*128 + ((((kk)*64) + quad*16) ^ ((l16 & 7) << 4))))
#define LDB3(b, nt, kk) (*(const bf16x8*)((const char*)smB + (b)*16384 + \
    (wn*64 + (nt)*16 + l16)*128 + ((((kk)*64) + quad*16) ^ ((l16 & 7) << 4))))
#define STGA4(b, t) do { \
    _Pragma("unroll") \
    for (int h = 0; h < 4; ++h) \
      GLOAD_LDS16(aBase + (size_t)(h*64) * DD + (t)*64, smA + (b)*16384 + h*4096 + wst); } while(0)
#define STGB2M(b, t) do { \
    _Pragma("unroll") \
    for (int h = 0; h < 2; ++h) \
      GLOAD_LDS16(bBase + (size_t)(h*64) * DD + (t)*64, smB + (b)*8192 + h*4096 + wst); } while(0)
#define MFMA_P(NT0) do { \
    __builtin_amdgcn_s_setprio(1); \
    _Pragma("unroll") \
    for (int mt = 0; mt < 4; ++mt) \
      _Pragma("unroll") \
      for (int nt = 0; nt < 2; ++nt) \
        _Pragma("unroll") \
        for (int kk = 0; kk < 2; ++kk) \
          acc[mt][(NT0) + nt] = __builtin_amdgcn_mfma_f32_16x16x32_bf16( \
              af[mt][kk], bf[(NT0) + nt][kk], acc[mt][(NT0) + nt], 0, 0, 0); \
    __builtin_amdgcn_s_setprio(0); } while(0)

#define GEMM_KLOOP \
  STGA4(0, 0); STGB2M(0, 0); \
  STGA4(1, 1); STGB2M(1, 1); \
  asm volatile("s_waitcnt vmcnt(6)" ::: "memory"); \
  __builtin_amdgcn_s_barrier(); \
  int bc = 0, bs = 2; \
  for (int t = 0; t < 32; ++t) { \
    _Pragma("unroll") \
    for (int mt = 0; mt < 4; ++mt) { af[mt][0] = LDA3(bc, mt, 0); af[mt][1] = LDA3(bc, mt, 1); } \
    _Pragma("unroll") \
    for (int nt = 0; nt < 2; ++nt) { bf[nt][0] = LDB3(bc, nt, 0); bf[nt][1] = LDB3(bc, nt, 1); } \
    if (t + 2 < 32) STGA4(bs, t + 2); \
    __builtin_amdgcn_s_barrier(); \
    asm volatile("s_waitcnt lgkmcnt(0)" ::: "memory"); \
    __builtin_amdgcn_sched_barrier(0); \
    MFMA_P(0); \
    __builtin_amdgcn_s_barrier(); \
    _Pragma("unroll") \
    for (int nt = 2; nt < 4; ++nt) { bf[nt][0] = LDB3(bc, nt, 0); bf[nt][1] = LDB3(bc, nt, 1); } \
    if (t + 2 < 32) { \
      STGB2M(bs, t + 2); \
      asm volatile("s_waitcnt vmcnt(6)" ::: "memory"); \
    } else { \
      asm volatile("s_waitcnt vmcnt(0)" ::: "memory"); \
    } \
    __builtin_amdgcn_s_barrier(); \
    asm volatile("s_waitcnt lgkmcnt(0)" ::: "memory"); \
    __builtin_amdgcn_sched_barrier(0); \
    MFMA_P(2); \
    __builtin_amdgcn_s_barrier(); \
    bc = (bc == 2) ? 0 : bc + 1; \
    bs = (bs == 2) ? 0 : bs + 1; \
  }

// ---------------- Fused QKV GEMM: 256x128 tiles, 768 blocks (3 clean rounds) ----
// RoPE fused in epilogue; Q scaled by log2(e)/sqrt(DH) (exp2-domain softmax).
__global__ __launch_bounds__(512, 1)
void gemm_qkv(const short* __restrict__ A,
              const short* __restrict__ Wq, const short* __restrict__ Wk,
              const short* __restrict__ Wv, const int* __restrict__ pos,
              short* __restrict__ Qo, short* __restrict__ Ko, short* __restrict__ Vo) {
  __shared__ __align__(16) short sm[73728];   // 144 KiB: A[3][256][64] | B[3][128][64]
  const int tid = threadIdx.x;
  const int lane = tid & 63;
  const int wave = tid >> 6;                  // 0..7
  const int quad = lane >> 4, l16 = lane & 15;
  const int wm = wave >> 1, wn = wave & 1;    // wave tile: 64 rows x 64 cols

  // bijective XCD swizzle (768 % 8 == 0): XCD j owns logical tiles [j*96, j*96+96)
  const int wid = (blockIdx.x & 7) * 96 + (blockIdx.x >> 3);
  const int wsel = wid >> 8;                  // 0=Q 1=K 2=V (wsel-major: per-round
  const int idr = wid & 255;                  //  working set = A + one weight matrix)
  const int bm = (idr >> 4) * 256;
  const int bn = (idr & 15) * 128;
  const short* Bw = (wsel == 0) ? Wq : (wsel == 1) ? Wk : Wv;
  short* Cout = (wsel == 0) ? Qo : (wsel == 1) ? Ko : Vo;

  short* smA = sm;                 // bufs at +0, +16384, +32768 shorts
  short* smB = sm + 49152;         // bufs at +0, +8192, +16384 shorts
  const int wst = wave * 512;      // wave's staging base within a 64-row group

  const int srow = tid >> 3;                          // 0..63
  const int scol = ((tid & 7) ^ (srow & 7)) * 8;      // pre-swizzled col (shorts)
  const short* aBase = A  + (size_t)(bm + srow) * DD + scol;
  const short* bBase = Bw + (size_t)(bn + srow) * DD + scol;

  f32x4 acc[4][4] = {};
  bf16x8 af[4][2], bf[4][2];

  GEMM_KLOOP

  // ---- RoPE in-register for Q/K (pairs = adjacent lanes via DPP xor1) ----
  if (wsel < 2) {
    const float post = (wsel == 0) ? 0.1275174306f : 1.0f;  // log2(e)/sqrt(128)
    float fr[4];
    #pragma unroll
    for (int nt = 0; nt < 4; ++nt) {
      int pi = wn * 32 + nt * 8 + (l16 >> 1);              // pair index 0..63
      fr[nt] = __expf(-0.14391156831f * (float)pi);        // theta^(-pi/64)
    }
    const float sgn = (l16 & 1) ? 1.0f : -1.0f;
    #pragma unroll
    for (int mt = 0; mt < 4; ++mt) {
      #pragma unroll
      for (int r = 0; r < 4; ++r) {
        int m = bm + wm*64 + mt*16 + quad*4 + r;
        float fp = (float)pos[m & 2047];
        #pragma unroll
        for (int nt = 0; nt < 4; ++nt) {
          float v = acc[mt][nt][r];
          float p = dppf<0xB1>(v);               // partner (d^1) value
          float ang = fp * fr[nt];
          float sn = __sinf(ang), cs = __cosf(ang);
          acc[mt][nt][r] = (v * cs + sgn * p * sn) * post;
        }
      }
    }
  }

  #pragma unroll
  for (int mt = 0; mt < 4; ++mt)
    #pragma unroll
    for (int nt = 0; nt < 4; ++nt)
      #pragma unroll
      for (int r = 0; r < 4; ++r) {
        int m = bm + wm*64 + mt*16 + quad*4 + r;
        int n = bn + wn*64 + nt*16 + l16;
        int b = m >> 11, s = m & 2047;
        int h = n >> 7,  d = n & 127;
        Cout[(((size_t)(b*HH + h)*SS + s)*DHH) + d] = f2b(acc[mt][nt][r]);
      }
}

// ---------------- O-projection GEMM: same template, 256 blocks = 1/CU -----------
__global__ __launch_bounds__(512, 1)
void gemm_o(const short* __restrict__ A, const short* __restrict__ Bw,
            float* __restrict__ Cout) {
  __shared__ __align__(16) short sm[73728];   // 144 KiB
  const int tid = threadIdx.x;
  const int lane = tid & 63;
  const int wave = tid >> 6;
  const int quad = lane >> 4, l16 = lane & 15;
  const int wm = wave >> 1, wn = wave & 1;

  const int wid = (blockIdx.x & 7) * 32 + (blockIdx.x >> 3);  // 256 % 8 == 0
  const int bm = (wid >> 4) * 256;
  const int bn = (wid & 15) * 128;

  short* smA = sm;
  short* smB = sm + 49152;
  const int wst = wave * 512;

  const int srow = tid >> 3;
  const int scol = ((tid & 7) ^ (srow & 7)) * 8;
  const short* aBase = A  + (size_t)(bm + srow) * DD + scol;
  const short* bBase = Bw + (size_t)(bn + srow) * DD + scol;

  f32x4 acc[4][4] = {};
  bf16x8 af[4][2], bf[4][2];

  GEMM_KLOOP

  #pragma unroll
  for (int mt = 0; mt < 4; ++mt)
    #pragma unroll
    for (int nt = 0; nt < 4; ++nt)
      #pragma unroll
      for (int r = 0; r < 4; ++r) {
        int m = bm + wm*64 + mt*16 + quad*4 + r;
        int n = bn + wn*64 + nt*16 + l16;
        Cout[(size_t)m * DD + n] = acc[mt][nt][r];
      }
}

// ---------------- Flash attention (causal), 128-row Q tile, 2 row-groups/wave ----
// 256 threads (4 waves); wave owns 32 q-rows (two 16-row MFMA strips). Each K/V
// fragment read from LDS feeds BOTH strips' MFMAs -> device-wide LDS read traffic
// halves vs the 64-row version (block-iters 16896 -> 8704). Grid 512 = 2/CU;
// co-resident pair (s, s+8) -> q-tiles i and 15-i: constant 34 iters/CU, same bh.
// Spill-free: ~196 VGPR under launch_bounds(256,2)'s 256 cap. K via global_load_lds
// (pre-swizzled source); V reg-prefetch with counted vmcnt(4) across the barrier.
__global__ __launch_bounds__(256, 2)
void attn(const short* __restrict__ Q, const short* __restrict__ K,
          const short* __restrict__ V, short* __restrict__ O) {
  __shared__ __align__(16) short Ks[64*128];    // 16 KB [key][dim], swizzled
  __shared__ __align__(16) short Vt[128*64];    // 16 KB [dim][key], swizzled
  __shared__ __align__(16) short Pb[4*32*64];   // 16 KB per-wave P (32 q), swizzled
  const int tid = threadIdx.x;
  const int lane = tid & 63, wave = tid >> 6;   // wave 0..3
  const int quad = lane >> 4, l16 = lane & 15;
  const int L = blockIdx.x;
  const int bh = L & 31;
  const int s = L >> 5;                         // 0..15
  const int i = (s < 8) ? s : 23 - s;           // q-tile index (128 rows each)
  const int b = bh >> 4, h = bh & 15;
  const short* Kg = K + (size_t)bh * SS * DHH;
  const short* Vg = V + (size_t)bh * SS * DHH;
  const int qb0 = i * 128 + wave * 32;          // wave's first q-row

  bf16x8 aq[2][4];
  #pragma unroll
  for (int t = 0; t < 2; ++t) {
    const short* qp = Q + ((size_t)bh * SS + qb0 + t*16 + l16) * DHH + quad*8;
    #pragma unroll
    for (int ks = 0; ks < 4; ++ks) aq[t][ks] = *(const bf16x8*)(qp + ks*32);
  }

  f32x4 o[2][8] = {};
  float mrow[2][4], lrow[2][4];
  #pragma unroll
  for (int t = 0; t < 2; ++t)
    #pragma unroll
    for (int r = 0; r < 4; ++r) { mrow[t][r] = -1e30f; lrow[t][r] = 0.f; }

  // K staging geometry (global_load_lds, pre-swizzled source; both-sides rule)
  const int skey0 = wave*16 + (lane >> 4);
  const int scolb = (lane & 15) << 4;
  // V staging geometry (reg transpose)
  const int vkp = (tid & 31) * 2;
  const int vds = (tid >> 5) * 16;

  const int nkt = 2*i + 2;
  int4 vreg[4];
  {
    const short* vp = Vg + (size_t)vkp * DHH + vds;
    vreg[0] = *(const int4*)vp;         vreg[1] = *(const int4*)(vp + 8);
    vreg[2] = *(const int4*)(vp + DHH); vreg[3] = *(const int4*)(vp + DHH + 8);
  }

  for (int kt = 0; kt < nkt; ++kt) {
    // ---- stage K(kt) direct to LDS (async, 4 x 1KB/wave) ----
    {
      const short* Kt = Kg + (size_t)kt * 64 * DHH;
      #pragma unroll
      for (int j = 0; j < 4; ++j) {
        int key = skey0 + j*4;
        GLOAD_LDS16(Kt + (size_t)key * DHH + ((scolb ^ ((key & 7) << 4)) >> 1),
                    Ks + wave*2048 + j*512);
      }
    }
    asm volatile("" ::: "memory");   // pin: V loads issue AFTER K gloads
    // ---- V(kt): transpose-write from regs, swizzled ----
    {
      const short* s0 = (const short*)&vreg[0];   // key vkp,   dims vds..+15
      const short* s1 = (const short*)&vreg[2];   // key vkp+1, dims vds..+15
      #pragma unroll
      for (int e = 0; e < 16; ++e) {
        int dim = vds + e;
        int val = (int)(unsigned short)s0[e] | ((int)(unsigned short)s1[e] << 16);
        *(int*)((char*)Vt + dim*128 + ((vkp*2) ^ ((dim & 7) << 4))) = val;
      }
    }
    // ---- prefetch V(kt+1); counted wait keeps it in flight across barrier ----
    if (kt + 1 < nkt) {
      const short* vp = Vg + (size_t)((kt+1)*64 + vkp) * DHH + vds;
      vreg[0] = *(const int4*)vp;         vreg[1] = *(const int4*)(vp + 8);
      vreg[2] = *(const int4*)(vp + DHH); vreg[3] = *(const int4*)(vp + DHH + 8);
      asm volatile("s_waitcnt vmcnt(4) lgkmcnt(0)" ::: "memory");  // K done, V in flight
    } else {
      asm volatile("s_waitcnt vmcnt(0) lgkmcnt(0)" ::: "memory");
    }
    __builtin_amdgcn_s_barrier();
    __builtin_amdgcn_sched_barrier(0);

    // ---- QK^T: 32 queries x 64 keys; each K fragment feeds both strips ----
    float sv[2][4][4];
    __builtin_amdgcn_s_setprio(1);
    #pragma unroll
    for (int nt = 0; nt < 4; ++nt) {
      f32x4 a0 = {0.f,0.f,0.f,0.f}, a1 = {0.f,0.f,0.f,0.f};
      #pragma unroll
      for (int ks = 0; ks < 4; ++ks) {
        int key = nt*16 + l16;
        bf16x8 bk = *(const bf16x8*)((const char*)Ks + key*256 +
                       ((ks*64 + quad*16) ^ ((key & 7) << 4)));
        a0 = __builtin_amdgcn_mfma_f32_16x16x32_bf16(aq[0][ks], bk, a0, 0, 0, 0);
        a1 = __builtin_amdgcn_mfma_f32_16x16x32_bf16(aq[1][ks], bk, a1, 0, 0, 0);
      }
      #pragma unroll
      for (int r = 0; r < 4; ++r) { sv[0][nt][r] = a0[r]; sv[1][nt][r] = a1[r]; }
    }
    __builtin_amdgcn_s_setprio(0);

    // ---- causal mask (only the last two tiles can straddle the diagonal) ----
    if (kt >= nkt - 2) {
      #pragma unroll
      for (int t = 0; t < 2; ++t)
        #pragma unroll
        for (int nt = 0; nt < 4; ++nt)
          #pragma unroll
          for (int r = 0; r < 4; ++r)
            if (kt*64 + nt*16 + l16 > qb0 + t*16 + quad*4 + r) sv[t][nt][r] = -1e30f;
    }
    // (fully-masked strip is safe: mx=-1e30 -> mnew=mrow, alpha=1, ls=0)

    // ---- online softmax (exp2 domain) + P pack, per strip ----
    #pragma unroll
    for (int t = 0; t < 2; ++t) {
      #pragma unroll
      for (int r = 0; r < 4; ++r) {
        float mx = fmaxf(fmaxf(sv[t][0][r], sv[t][1][r]), fmaxf(sv[t][2][r], sv[t][3][r]));
        mx = rmax16(mx);
        float mnew = fmaxf(mrow[t][r], mx);
        float alpha = EXP2F(mrow[t][r] - mnew);
        float ls = 0.f;
        #pragma unroll
        for (int nt = 0; nt < 4; ++nt) {
          float pv = EXP2F(sv[t][nt][r] - mnew);
          sv[t][nt][r] = pv; ls += pv;
        }
        ls = rsum16(ls);
        lrow[t][r] = lrow[t][r] * alpha + ls;
        mrow[t][r] = mnew;
        #pragma unroll
        for (int nt = 0; nt < 8; ++nt) o[t][nt][r] *= alpha;
      }
      #pragma unroll
      for (int nt = 0; nt < 4; ++nt)
        #pragma unroll
        for (int r = 0; r < 4; ++r) {
          int qr = t*16 + quad*4 + r;               // 0..31 within wave region
          *(short*)((char*)Pb + wave*4096 + qr*128 +
                    (((nt*16 + l16)*2) ^ ((qr & 7) << 4))) = f2b_fast(sv[t][nt][r]);
        }
    }

    bf16x8 ap[2][2];
    #pragma unroll
    for (int t = 0; t < 2; ++t)
      #pragma unroll
      for (int k2 = 0; k2 < 2; ++k2)
        ap[t][k2] = *(const bf16x8*)((const char*)Pb + wave*4096 + (t*16 + l16)*128 +
                      ((k2*64 + quad*16) ^ ((l16 & 7) << 4)));

    // ---- PV: each V fragment feeds both strips ----
    __builtin_amdgcn_s_setprio(1);
    #pragma unroll
    for (int k2 = 0; k2 < 2; ++k2)
      #pragma unroll
      for (int nt = 0; nt < 8; ++nt) {
        int d = nt*16 + l16;
        bf16x8 bv = *(const bf16x8*)((const char*)Vt + d*128 +
                       ((k2*64 + quad*16) ^ ((d & 7) << 4)));
        o[0][nt] = __builtin_amdgcn_mfma_f32_16x16x32_bf16(ap[0][k2], bv, o[0][nt], 0, 0, 0);
        o[1][nt] = __builtin_amdgcn_mfma_f32_16x16x32_bf16(ap[1][k2], bv, o[1][nt], 0, 0, 0);
      }
    __builtin_amdgcn_s_setprio(0);

    // ---- end of iter: LDS reads drained; V prefetch stays in flight ----
    asm volatile("s_waitcnt lgkmcnt(0)" ::: "memory");
    __builtin_amdgcn_s_barrier();
    __builtin_amdgcn_sched_barrier(0);
  }

  #pragma unroll
  for (int t = 0; t < 2; ++t)
    #pragma unroll
    for (int nt = 0; nt < 8; ++nt)
      #pragma unroll
      for (int r = 0; r < 4; ++r) {
        int q = qb0 + t*16 + quad*4 + r;
        float v = o[t][nt][r] / lrow[t][r];
        O[((size_t)(b*SS + q)) * DD + h*DHH + nt*16 + l16] = f2b(v);
      }
}

extern "C" void kernel_launch(void* const* d_in, const int* in_sizes, int n_in,
                              void* d_out, int out_size, void* d_ws, size_t ws_size,
                              hipStream_t stream) {
  const float* x  = (const float*)d_in[0];
  const int* pos  = (const int*)d_in[1];
  const float* Wq = (const float*)d_in[2];
  const float* Wk = (const float*)d_in[3];
  const float* Wv = (const float*)d_in[4];
  const float* Wo = (const float*)d_in[5];

  char* ws = (char*)d_ws;
  short* xb  = (short*)(ws);
  short* wqb = (short*)(ws + 16777216);
  short* wkb = (short*)(ws + 25165824);
  short* wvb = (short*)(ws + 33554432);
  short* wob = (short*)(ws + 41943040);
  short* Qb  = (short*)(ws + 50331648);
  short* Kb  = (short*)(ws + 67108864);
  short* Vb  = (short*)(ws + 83886080);
  short* Ob  = (short*)(ws + 100663296);

  cvt_all<<<24576, 256, 0, stream>>>(x, Wq, Wk, Wv, Wo, xb, wqb, wkb, wvb, wob);

  // fused QKV: 768 blocks (3 mats x 16 M x 16 N) = 3 clean dispatch rounds
  gemm_qkv<<<768, 512, 0, stream>>>(xb, wqb, wkb, wvb, pos, Qb, Kb, Vb);

  // attn: 512 blocks (16 q-tiles x 32 bh) = 2/CU, balanced pairs
  attn<<<512, 256, 0, stream>>>(Qb, Kb, Vb, Ob);

  // O-projection: 256 blocks (16 M x 16 N) = exactly 1 block/CU
  gemm_o<<<256, 512, 0, stream>>>(Ob, wob, (float*)d_out);
}